// Round 7
// baseline (613.333 us; speedup 1.0000x reference)
//
#include <hip/hip_runtime.h>
#include <hip/hip_bf16.h>

typedef float f32x4 __attribute__((ext_vector_type(4)));
typedef short bf16x8 __attribute__((ext_vector_type(8)));

#define NB 50000
#define NK 32
#define NH 128
#define NL 64

static __device__ __forceinline__ unsigned short f2bf(float f) {
    unsigned int u = __float_as_uint(f);
    u += 0x7fffu + ((u >> 16) & 1u);
    return (unsigned short)(u >> 16);
}
static __device__ __forceinline__ float bf2f(unsigned short u) {
    return __uint_as_float(((unsigned int)u) << 16);
}
static __device__ __forceinline__ float bflo(unsigned int u) { return __uint_as_float(u << 16); }
static __device__ __forceinline__ float bfhi(unsigned int u) { return __uint_as_float(u & 0xffff0000u); }

__global__ void kl_zero_kernel(float* out) {
    if (threadIdx.x == 0 && blockIdx.x == 0) out[(size_t)NB * NH] = 0.0f;
}

// ---------------- K0: Wvo = Wv@Wo (f32, ws), bvo = b_v@Wo + b_o ----------------
__global__ void __launch_bounds__(256) wvo_kernel(const float* __restrict__ W_v,
                                                  const float* __restrict__ W_o,
                                                  const float* __restrict__ b_v,
                                                  const float* __restrict__ b_o,
                                                  float* __restrict__ wvo_ws,
                                                  float* __restrict__ bvo_ws)
{
    const int t = threadIdx.x;
    for (int e = t; e < 64 * 128; e += 256) {
        int d = e >> 7, h = e & 127;
        float s = 0.f;
#pragma unroll 8
        for (int c = 0; c < 64; ++c) s += W_v[d * 64 + c] * W_o[c * 128 + h];
        wvo_ws[e] = s;
    }
    if (t < 128) {
        float s = b_o[t];
#pragma unroll 8
        for (int c = 0; c < 64; ++c) s += b_v[c] * W_o[c * 128 + t];
        bvo_ws[t] = s;
    }
}

// ---------------- K1: qk = (self@Wq + b_q) @ Wk^T   (f32 out to ws) ----------------
__global__ void __launch_bounds__(256) qk_kernel(const float* __restrict__ self_feat,
                                                 const float* __restrict__ W_q,
                                                 const float* __restrict__ b_q,
                                                 const float* __restrict__ W_k,
                                                 float* __restrict__ qk_ws)
{
    __shared__ __align__(16) unsigned short A[32 * 128];   // self tile, swizzled
    __shared__ __align__(16) unsigned short ZQ[32 * 64];   // q tile bf16, swizzled
    const int t = threadIdx.x, w = t >> 6, l = t & 63, g = l >> 4, li = l & 15;

    // stage-1 B frags: q cols c = li+16w
    bf16x8 Bq[4];
#pragma unroll
    for (int s = 0; s < 4; ++s) {
        int k0 = 32 * s + 8 * g, c = li + 16 * w;
        bf16x8 f;
#pragma unroll
        for (int j = 0; j < 8; ++j) f[j] = (short)f2bf(W_q[(k0 + j) * 64 + c]);
        Bq[s] = f;
    }
    // stage-2 B frags: Wk^T -> element (k, d=li+16w) = W_k[d][k]
    bf16x8 Bk[2];
#pragma unroll
    for (int s = 0; s < 2; ++s) {
        int k0 = 32 * s + 8 * g, d = li + 16 * w;
        bf16x8 f;
#pragma unroll
        for (int j = 0; j < 8; ++j) f[j] = (short)f2bf(W_k[d * 64 + k0 + j]);
        Bk[s] = f;
    }
    const float bq = b_q[li + 16 * w];
    const int n0 = blockIdx.x * 32;

    {   // stage self tile
        int row = t >> 3, c0 = (t & 7) * 16;
        float x[16];
        if (n0 + row < NB) {
            const float* src = self_feat + (size_t)(n0 + row) * NH + c0;
#pragma unroll
            for (int i = 0; i < 4; ++i) {
                float4 v4 = ((const float4*)src)[i];
                x[4 * i] = v4.x; x[4 * i + 1] = v4.y; x[4 * i + 2] = v4.z; x[4 * i + 3] = v4.w;
            }
        } else {
#pragma unroll
            for (int i = 0; i < 16; ++i) x[i] = 0.f;
        }
        alignas(16) unsigned short yb[16];
#pragma unroll
        for (int i = 0; i < 16; ++i) yb[i] = f2bf(x[i]);
        int boff = row * 256 + c0 * 2;
        *(int4*)((char*)A + ((boff) ^ ((row & 7) << 4))) = *(int4*)&yb[0];
        *(int4*)((char*)A + ((boff + 16) ^ ((row & 7) << 4))) = *(int4*)&yb[8];
    }
    __syncthreads();

    const f32x4 zero4 = {0.f, 0.f, 0.f, 0.f};
    f32x4 acc[2] = {zero4, zero4};
#pragma unroll
    for (int s = 0; s < 4; ++s) {
        bf16x8 A0 = *(const bf16x8*)((const char*)A + ((li * 256 + s * 64 + g * 16) ^ ((li & 7) << 4)));
        bf16x8 A1 = *(const bf16x8*)((const char*)A + (((16 + li) * 256 + s * 64 + g * 16) ^ ((li & 7) << 4)));
        acc[0] = __builtin_amdgcn_mfma_f32_16x16x32_bf16(A0, Bq[s], acc[0], 0, 0, 0);
        acc[1] = __builtin_amdgcn_mfma_f32_16x16x32_bf16(A1, Bq[s], acc[1], 0, 0, 0);
    }
    // q -> bf16 tile (C-layout: row=16mt+4g+r, col=li+16w)
#pragma unroll
    for (int mt = 0; mt < 2; ++mt)
#pragma unroll
        for (int r = 0; r < 4; ++r) {
            int row = 16 * mt + 4 * g + r, c = li + 16 * w;
            *(unsigned short*)((char*)ZQ + ((row * 128 + c * 2) ^ ((row & 7) << 4))) = f2bf(acc[mt][r] + bq);
        }
    __syncthreads();

    f32x4 acc2[2] = {zero4, zero4};
#pragma unroll
    for (int s = 0; s < 2; ++s) {
        bf16x8 A0 = *(const bf16x8*)((const char*)ZQ + ((li * 128 + s * 64 + g * 16) ^ ((li & 7) << 4)));
        bf16x8 A1 = *(const bf16x8*)((const char*)ZQ + (((16 + li) * 128 + s * 64 + g * 16) ^ (((16 + li) & 7) << 4)));
        acc2[0] = __builtin_amdgcn_mfma_f32_16x16x32_bf16(A0, Bk[s], acc2[0], 0, 0, 0);
        acc2[1] = __builtin_amdgcn_mfma_f32_16x16x32_bf16(A1, Bk[s], acc2[1], 0, 0, 0);
    }
#pragma unroll
    for (int mt = 0; mt < 2; ++mt)
#pragma unroll
        for (int r = 0; r < 4; ++r) {
            int row = 16 * mt + 4 * g + r;
            if (n0 + row < NB)
                qk_ws[(size_t)(n0 + row) * 64 + li + 16 * w] = acc2[mt][r];
        }
}

// ---------------- K2: fully fused main kernel (8 nodes/block, 5 barriers/node) ----------
__global__ void __launch_bounds__(256) fz_kernel(
    const float* __restrict__ neighbor_feat, const float* __restrict__ trust_mask,
    const float* __restrict__ eps_g,
    const float* __restrict__ pre_g, const float* __restrict__ pre_b,
    const float* __restrict__ W_mu, const float* __restrict__ b_mu,
    const float* __restrict__ W_lv, const float* __restrict__ b_lv,
    const float* __restrict__ post_g, const float* __restrict__ post_b,
    const float* __restrict__ qk_ws, const float* __restrict__ wvo_ws,
    const float* __restrict__ bvo_ws,
    float* __restrict__ out)
{
    __shared__ __align__(16) unsigned short A[32 * 128];  // 8KB bf16 swizzled
    __shared__ float muv[32 * 136];                       // 17.4KB
    __shared__ unsigned int WvoP[64 * 64];                // 16KB: [c][hp] packs h=hp(lo), h=hp+64(hi)
    __shared__ float2 s_pgb[128];
    __shared__ float s_bmu[64], s_blv[64], s_pg[64], s_pb[64];
    __shared__ float bvo_l[128];
    __shared__ float logit_l[32];
    __shared__ float zpart[4][64];
    __shared__ float zbar_l[64];
    __shared__ float klw[4];

    const int t = threadIdx.x, w = t >> 6, l = t & 63, g = l >> 4, li = l & 15;

    if (t < 128) { s_pgb[t] = make_float2(pre_g[t], pre_b[t]); bvo_l[t] = bvo_ws[t]; }
    if (t < 64) { s_bmu[t] = b_mu[t]; s_blv[t] = b_lv[t]; s_pg[t] = post_g[t]; s_pb[t] = post_b[t]; }
    for (int e = t; e < 4096; e += 256) {
        int c = e >> 6, hp = e & 63;
        WvoP[e] = (unsigned)f2bf(wvo_ws[c * 128 + hp]) | ((unsigned)f2bf(wvo_ws[c * 128 + hp + 64]) << 16);
    }
    // GEMM1 B-frags: waves 0,1 -> W_mu cols 0-31/32-63; waves 2,3 -> W_lv
    bf16x8 Wml[2][4];
    {
        const float* Wsrc = (w < 2) ? W_mu : W_lv;
        int cb = 32 * (w & 1) + li;
#pragma unroll
        for (int ntp = 0; ntp < 2; ++ntp)
#pragma unroll
            for (int s = 0; s < 4; ++s) {
                int k0 = 32 * s + 8 * g, c = cb + 16 * ntp;
                bf16x8 f;
#pragma unroll
                for (int j = 0; j < 8; ++j) f[j] = (short)f2bf(Wsrc[(k0 + j) * 64 + c]);
                Wml[ntp][s] = f;
            }
    }
    __syncthreads();

    const int row = t >> 3;          // 0..31 (node-neighbor index for this thread)
    const int c0 = (t & 7) * 16;     // P0 col group
    const int l0 = (t & 7) * 8;      // P2 col group
    int bn = blockIdx.x * 8;         // 6250*8 = 50000 exact

    float x[16], ee[8], qk8[8], trr;
    {   // prologue prefetch
        const float* src = neighbor_feat + ((size_t)bn * NK + row) * NH + c0;
#pragma unroll
        for (int i = 0; i < 4; ++i) {
            float4 v4 = ((const float4*)src)[i];
            x[4 * i] = v4.x; x[4 * i + 1] = v4.y; x[4 * i + 2] = v4.z; x[4 * i + 3] = v4.w;
        }
        const float* ep = eps_g + ((size_t)bn * NK + row) * NL + l0;
        float4 e0 = ((const float4*)ep)[0], e1 = ((const float4*)ep)[1];
        ee[0] = e0.x; ee[1] = e0.y; ee[2] = e0.z; ee[3] = e0.w;
        ee[4] = e1.x; ee[5] = e1.y; ee[6] = e1.z; ee[7] = e1.w;
        const float* qp = qk_ws + (size_t)bn * 64 + l0;
        float4 q0 = ((const float4*)qp)[0], q1 = ((const float4*)qp)[1];
        qk8[0] = q0.x; qk8[1] = q0.y; qk8[2] = q0.z; qk8[3] = q0.w;
        qk8[4] = q1.x; qk8[5] = q1.y; qk8[6] = q1.z; qk8[7] = q1.w;
        trr = trust_mask[(size_t)bn * NK + row];
    }

    float kl_acc = 0.f;
    const f32x4 zero4 = {0.f, 0.f, 0.f, 0.f};

    for (int i = 0; i < 8; ++i, ++bn) {
        const int bnx = (bn + 1 < NB) ? bn + 1 : bn;

        // ---- P0: pre-LN -> bf16 A tile ----
        float s1 = 0.f;
#pragma unroll
        for (int j = 0; j < 16; ++j) s1 += x[j];
        s1 += __shfl_xor(s1, 1); s1 += __shfl_xor(s1, 2); s1 += __shfl_xor(s1, 4);
        float mean = s1 * (1.f / 128.f);
        float s2 = 0.f;
#pragma unroll
        for (int j = 0; j < 16; ++j) { float d = x[j] - mean; s2 += d * d; }
        s2 += __shfl_xor(s2, 1); s2 += __shfl_xor(s2, 2); s2 += __shfl_xor(s2, 4);
        float inv = rsqrtf(s2 * (1.f / 128.f) + 1e-5f);
        alignas(16) unsigned short yb[16];
#pragma unroll
        for (int j = 0; j < 16; ++j) {
            float2 gb = s_pgb[c0 + j];
            yb[j] = f2bf((x[j] - mean) * inv * gb.x + gb.y);
        }
        {
            int boff = row * 256 + c0 * 2;
            *(int4*)((char*)A + ((boff) ^ ((row & 7) << 4))) = *(int4*)&yb[0];
            *(int4*)((char*)A + ((boff + 16) ^ ((row & 7) << 4))) = *(int4*)&yb[8];
        }
        {   // reissue neighbor for next node
            const float* src = neighbor_feat + ((size_t)bnx * NK + row) * NH + c0;
#pragma unroll
            for (int j = 0; j < 4; ++j) {
                float4 v4 = ((const float4*)src)[j];
                x[4 * j] = v4.x; x[4 * j + 1] = v4.y; x[4 * j + 2] = v4.z; x[4 * j + 3] = v4.w;
            }
        }
        __syncthreads();   // b1

        // ---- P1: GEMM1: wave w -> cols 32w..32w+31 of [mu|lv] ----
        f32x4 acc[2][2];
        acc[0][0] = zero4; acc[0][1] = zero4; acc[1][0] = zero4; acc[1][1] = zero4;
#pragma unroll
        for (int s = 0; s < 4; ++s) {
            bf16x8 A0 = *(const bf16x8*)((const char*)A + ((li * 256 + s * 64 + g * 16) ^ ((li & 7) << 4)));
            bf16x8 A1 = *(const bf16x8*)((const char*)A + (((16 + li) * 256 + s * 64 + g * 16) ^ ((li & 7) << 4)));
#pragma unroll
            for (int ntp = 0; ntp < 2; ++ntp) {
                acc[0][ntp] = __builtin_amdgcn_mfma_f32_16x16x32_bf16(A0, Wml[ntp][s], acc[0][ntp], 0, 0, 0);
                acc[1][ntp] = __builtin_amdgcn_mfma_f32_16x16x32_bf16(A1, Wml[ntp][s], acc[1][ntp], 0, 0, 0);
            }
        }
#pragma unroll
        for (int mt = 0; mt < 2; ++mt)
#pragma unroll
            for (int ntp = 0; ntp < 2; ++ntp)
#pragma unroll
                for (int r = 0; r < 4; ++r)
                    muv[(16 * mt + 4 * g + r) * 136 + 32 * w + 16 * ntp + li] = acc[mt][ntp][r];
        __syncthreads();   // b2

        // ---- P2: reparam + KL + post-LN (z stays in registers, f32) ----
        f32x4 mu0 = *(const f32x4*)&muv[row * 136 + l0];
        f32x4 mu1 = *(const f32x4*)&muv[row * 136 + l0 + 4];
        f32x4 lv0 = *(const f32x4*)&muv[row * 136 + 64 + l0];
        f32x4 lv1 = *(const f32x4*)&muv[row * 136 + 64 + l0 + 4];
        float zr[8];
#pragma unroll
        for (int j = 0; j < 8; ++j) {
            float mu = ((j < 4) ? mu0[j & 3] : mu1[j & 3]) + s_bmu[l0 + j];
            float lv = ((j < 4) ? lv0[j & 3] : lv1[j & 3]) + s_blv[l0 + j];
            float eh = __expf(0.5f * lv);
            kl_acc += 1.f + lv - mu * mu - eh * eh;
            zr[j] = mu + ee[j] * eh;
        }
        {   // reissue eps
            const float* ep = eps_g + ((size_t)bnx * NK + row) * NL + l0;
            float4 e0 = ((const float4*)ep)[0], e1 = ((const float4*)ep)[1];
            ee[0] = e0.x; ee[1] = e0.y; ee[2] = e0.z; ee[3] = e0.w;
            ee[4] = e1.x; ee[5] = e1.y; ee[6] = e1.z; ee[7] = e1.w;
        }
        float zs = 0.f;
#pragma unroll
        for (int j = 0; j < 8; ++j) zs += zr[j];
        zs += __shfl_xor(zs, 1); zs += __shfl_xor(zs, 2); zs += __shfl_xor(zs, 4);
        float zm = zs * (1.f / 64.f);
        float zv = 0.f;
#pragma unroll
        for (int j = 0; j < 8; ++j) { float d = zr[j] - zm; zv += d * d; }
        zv += __shfl_xor(zv, 1); zv += __shfl_xor(zv, 2); zv += __shfl_xor(zv, 4);
        float zi = rsqrtf(zv * (1.f / 64.f) + 1e-5f);
#pragma unroll
        for (int j = 0; j < 8; ++j)
            zr[j] = (zr[j] - zm) * zi * s_pg[l0 + j] + s_pb[l0 + j];

        // ---- P2b: logit[row] = 0.125*(z[row].qk) + log(trust) ----
        float lg = 0.f;
#pragma unroll
        for (int j = 0; j < 8; ++j) lg += zr[j] * qk8[j];
        lg += __shfl_xor(lg, 1); lg += __shfl_xor(lg, 2); lg += __shfl_xor(lg, 4);
        if ((l & 7) == 0) logit_l[row] = lg * 0.125f + __logf(trr + 1e-6f);
        {   // reissue qk + trust
            const float* qp = qk_ws + (size_t)bnx * 64 + l0;
            float4 q0 = ((const float4*)qp)[0], q1 = ((const float4*)qp)[1];
            qk8[0] = q0.x; qk8[1] = q0.y; qk8[2] = q0.z; qk8[3] = q0.w;
            qk8[4] = q1.x; qk8[5] = q1.y; qk8[6] = q1.z; qk8[7] = q1.w;
            trr = trust_mask[(size_t)bnx * NK + row];
        }
        __syncthreads();   // b3

        // ---- P3: softmax (redundant per thread; only att[row] needed) ----
        float mx = logit_l[0];
#pragma unroll
        for (int n = 1; n < 32; ++n) mx = fmaxf(mx, logit_l[n]);
        float den = 0.f;
#pragma unroll
        for (int n = 0; n < 32; ++n) den += __expf(logit_l[n] - mx);
        float att = __expf(logit_l[row] - mx) / den;

        // ---- P4: zbar wave-partials ----
        float av[8];
#pragma unroll
        for (int j = 0; j < 8; ++j) av[j] = att * zr[j];
#pragma unroll
        for (int j = 0; j < 8; ++j) {
            av[j] += __shfl_xor(av[j], 8);
            av[j] += __shfl_xor(av[j], 16);
            av[j] += __shfl_xor(av[j], 32);
        }
        if (l < 8) {
            float4 p0 = {av[0], av[1], av[2], av[3]};
            float4 p1 = {av[4], av[5], av[6], av[7]};
            ((float4*)&zpart[w][8 * l])[0] = p0;
            ((float4*)&zpart[w][8 * l])[1] = p1;
        }
        __syncthreads();   // b4

        if (t < 64) zbar_l[t] = zpart[0][t] + zpart[1][t] + zpart[2][t] + zpart[3][t];
        __syncthreads();   // b5

        // ---- P5: out = zbar @ Wvo + bvo (threads 0..127) ----
        if (t < 128) {
            int hp = t & 63, hi = t >> 6;
            float o = 0.f;
#pragma unroll 8
            for (int c = 0; c < 64; ++c) {
                unsigned int W2 = WvoP[c * 64 + hp];
                o += zbar_l[c] * (hi ? bfhi(W2) : bflo(W2));
            }
            out[(size_t)bn * NH + 64 * hi + hp] = o + bvo_l[64 * hi + hp];
        }
    }

    // ---- KL reduction ----
#pragma unroll
    for (int msk = 1; msk < 64; msk <<= 1) kl_acc += __shfl_xor(kl_acc, msk);
    if (l == 0) klw[w] = kl_acc;
    __syncthreads();
    if (t == 0) {
        float tot = klw[0] + klw[1] + klw[2] + klw[3];
        atomicAdd(out + (size_t)NB * NH, tot * (-0.5f * 0.001f / ((float)NB * NK)));
    }
}

extern "C" void kernel_launch(void* const* d_in, const int* in_sizes, int n_in,
                              void* d_out, int out_size, void* d_ws, size_t ws_size,
                              hipStream_t stream) {
    const float* self_feat     = (const float*)d_in[0];
    const float* neighbor_feat = (const float*)d_in[1];
    const float* trust_mask    = (const float*)d_in[2];
    const float* eps           = (const float*)d_in[3];
    const float* pre_g  = (const float*)d_in[4];
    const float* pre_b  = (const float*)d_in[5];
    const float* W_mu   = (const float*)d_in[6];
    const float* b_mu   = (const float*)d_in[7];
    const float* W_lv   = (const float*)d_in[8];
    const float* b_lv   = (const float*)d_in[9];
    const float* post_g = (const float*)d_in[10];
    const float* post_b = (const float*)d_in[11];
    const float* W_q    = (const float*)d_in[12];
    const float* b_q    = (const float*)d_in[13];
    const float* W_k    = (const float*)d_in[14];
    const float* W_v    = (const float*)d_in[16];
    const float* b_v    = (const float*)d_in[17];
    const float* W_o    = (const float*)d_in[18];
    const float* b_o    = (const float*)d_in[19];
    float* out = (float*)d_out;

    // ws: qk f32 [NB,64] (12.8MB) | Wvo f32 [64,128] | bvo f32 [128]
    float* qk_ws  = (float*)d_ws;
    float* wvo_ws = qk_ws + (size_t)NB * 64;
    float* bvo_ws = wvo_ws + 64 * 128;

    hipLaunchKernelGGL(kl_zero_kernel, dim3(1), dim3(64), 0, stream, out);
    hipLaunchKernelGGL(wvo_kernel, dim3(1), dim3(256), 0, stream, W_v, W_o, b_v, b_o, wvo_ws, bvo_ws);
    hipLaunchKernelGGL(qk_kernel, dim3((NB + 31) / 32), dim3(256), 0, stream,
                       self_feat, W_q, b_q, W_k, qk_ws);
    hipLaunchKernelGGL(fz_kernel, dim3(NB / 8), dim3(256), 0, stream,
                       neighbor_feat, trust_mask, eps, pre_g, pre_b,
                       W_mu, b_mu, W_lv, b_lv, post_g, post_b,
                       qk_ws, wvo_ws, bvo_ws, out);
}

// Round 8
// 604.032 us; speedup vs baseline: 1.0154x; 1.0154x over previous
//
#include <hip/hip_runtime.h>
#include <hip/hip_bf16.h>

typedef float f32x4 __attribute__((ext_vector_type(4)));
typedef short bf16x8 __attribute__((ext_vector_type(8)));

#define NB 50000
#define NK 32
#define NH 128
#define NL 64

static __device__ __forceinline__ unsigned short f2bf(float f) {
    unsigned int u = __float_as_uint(f);
    u += 0x7fffu + ((u >> 16) & 1u);
    return (unsigned short)(u >> 16);
}
static __device__ __forceinline__ float bf2f(unsigned short u) {
    return __uint_as_float(((unsigned int)u) << 16);
}
static __device__ __forceinline__ float bflo(unsigned int u) { return __uint_as_float(u << 16); }
static __device__ __forceinline__ float bfhi(unsigned int u) { return __uint_as_float(u & 0xffff0000u); }

__global__ void kl_zero_kernel(float* out) {
    if (threadIdx.x == 0 && blockIdx.x == 0) out[(size_t)NB * NH] = 0.0f;
}

// ---------------- K0: Wvo = Wv@Wo (f32, ws), bvo = b_v@Wo + b_o ----------------
__global__ void __launch_bounds__(256) wvo_kernel(const float* __restrict__ W_v,
                                                  const float* __restrict__ W_o,
                                                  const float* __restrict__ b_v,
                                                  const float* __restrict__ b_o,
                                                  float* __restrict__ wvo_ws,
                                                  float* __restrict__ bvo_ws)
{
    const int t = threadIdx.x;
    for (int e = t; e < 64 * 128; e += 256) {
        int d = e >> 7, h = e & 127;
        float s = 0.f;
#pragma unroll 8
        for (int c = 0; c < 64; ++c) s += W_v[d * 64 + c] * W_o[c * 128 + h];
        wvo_ws[e] = s;
    }
    if (t < 128) {
        float s = b_o[t];
#pragma unroll 8
        for (int c = 0; c < 64; ++c) s += b_v[c] * W_o[c * 128 + t];
        bvo_ws[t] = s;
    }
}

// ---------------- K1: qk = (self@Wq + b_q) @ Wk^T   (f32 out to ws) ----------------
__global__ void __launch_bounds__(256) qk_kernel(const float* __restrict__ self_feat,
                                                 const float* __restrict__ W_q,
                                                 const float* __restrict__ b_q,
                                                 const float* __restrict__ W_k,
                                                 float* __restrict__ qk_ws)
{
    __shared__ __align__(16) unsigned short A[32 * 128];   // self tile, swizzled
    __shared__ __align__(16) unsigned short ZQ[32 * 64];   // q tile bf16, swizzled
    const int t = threadIdx.x, w = t >> 6, l = t & 63, g = l >> 4, li = l & 15;

    bf16x8 Bq[4];
#pragma unroll
    for (int s = 0; s < 4; ++s) {
        int k0 = 32 * s + 8 * g, c = li + 16 * w;
        bf16x8 f;
#pragma unroll
        for (int j = 0; j < 8; ++j) f[j] = (short)f2bf(W_q[(k0 + j) * 64 + c]);
        Bq[s] = f;
    }
    bf16x8 Bk[2];
#pragma unroll
    for (int s = 0; s < 2; ++s) {
        int k0 = 32 * s + 8 * g, d = li + 16 * w;
        bf16x8 f;
#pragma unroll
        for (int j = 0; j < 8; ++j) f[j] = (short)f2bf(W_k[d * 64 + k0 + j]);
        Bk[s] = f;
    }
    const float bq = b_q[li + 16 * w];
    const int n0 = blockIdx.x * 32;

    {
        int row = t >> 3, c0 = (t & 7) * 16;
        float x[16];
        if (n0 + row < NB) {
            const float* src = self_feat + (size_t)(n0 + row) * NH + c0;
#pragma unroll
            for (int i = 0; i < 4; ++i) {
                float4 v4 = ((const float4*)src)[i];
                x[4 * i] = v4.x; x[4 * i + 1] = v4.y; x[4 * i + 2] = v4.z; x[4 * i + 3] = v4.w;
            }
        } else {
#pragma unroll
            for (int i = 0; i < 16; ++i) x[i] = 0.f;
        }
        alignas(16) unsigned short yb[16];
#pragma unroll
        for (int i = 0; i < 16; ++i) yb[i] = f2bf(x[i]);
        int boff = row * 256 + c0 * 2;
        *(int4*)((char*)A + ((boff) ^ ((row & 7) << 4))) = *(int4*)&yb[0];
        *(int4*)((char*)A + ((boff + 16) ^ ((row & 7) << 4))) = *(int4*)&yb[8];
    }
    __syncthreads();

    const f32x4 zero4 = {0.f, 0.f, 0.f, 0.f};
    f32x4 acc[2] = {zero4, zero4};
#pragma unroll
    for (int s = 0; s < 4; ++s) {
        bf16x8 A0 = *(const bf16x8*)((const char*)A + ((li * 256 + s * 64 + g * 16) ^ ((li & 7) << 4)));
        bf16x8 A1 = *(const bf16x8*)((const char*)A + (((16 + li) * 256 + s * 64 + g * 16) ^ ((li & 7) << 4)));
        acc[0] = __builtin_amdgcn_mfma_f32_16x16x32_bf16(A0, Bq[s], acc[0], 0, 0, 0);
        acc[1] = __builtin_amdgcn_mfma_f32_16x16x32_bf16(A1, Bq[s], acc[1], 0, 0, 0);
    }
#pragma unroll
    for (int mt = 0; mt < 2; ++mt)
#pragma unroll
        for (int r = 0; r < 4; ++r) {
            int row = 16 * mt + 4 * g + r, c = li + 16 * w;
            *(unsigned short*)((char*)ZQ + ((row * 128 + c * 2) ^ ((row & 7) << 4))) = f2bf(acc[mt][r] + bq);
        }
    __syncthreads();

    f32x4 acc2[2] = {zero4, zero4};
#pragma unroll
    for (int s = 0; s < 2; ++s) {
        bf16x8 A0 = *(const bf16x8*)((const char*)ZQ + ((li * 128 + s * 64 + g * 16) ^ ((li & 7) << 4)));
        bf16x8 A1 = *(const bf16x8*)((const char*)ZQ + (((16 + li) * 128 + s * 64 + g * 16) ^ (((16 + li) & 7) << 4)));
        acc2[0] = __builtin_amdgcn_mfma_f32_16x16x32_bf16(A0, Bk[s], acc2[0], 0, 0, 0);
        acc2[1] = __builtin_amdgcn_mfma_f32_16x16x32_bf16(A1, Bk[s], acc2[1], 0, 0, 0);
    }
#pragma unroll
    for (int mt = 0; mt < 2; ++mt)
#pragma unroll
        for (int r = 0; r < 4; ++r) {
            int row = 16 * mt + 4 * g + r;
            if (n0 + row < NB)
                qk_ws[(size_t)(n0 + row) * 64 + li + 16 * w] = acc2[mt][r];
        }
}

// ---------------- K2: fused main, wave-per-node, ZERO in-loop barriers ----------------
__global__ void __launch_bounds__(256, 1) fzw_kernel(
    const float* __restrict__ neighbor_feat, const float* __restrict__ trust_mask,
    const float* __restrict__ eps_g,
    const float* __restrict__ pre_g, const float* __restrict__ pre_b,
    const float* __restrict__ W_mu, const float* __restrict__ b_mu,
    const float* __restrict__ W_lv, const float* __restrict__ b_lv,
    const float* __restrict__ post_g, const float* __restrict__ post_b,
    const float* __restrict__ qk_ws, const float* __restrict__ wvo_ws,
    const float* __restrict__ bvo_ws,
    float* __restrict__ out)
{
    __shared__ uint4 WmlB[8 * 4 * 64];        // 32KB: [nt][s][lane] bf16 B-frag blob (nt<4 mu, else lv)
    __shared__ unsigned int WvoP[64 * 64];    // 16KB: [c][hp] packs h=hp (lo), h=hp+64 (hi)
    __shared__ float2 s_pgb[128];             // 1KB
    __shared__ float zbar_l[4][64];           // 1KB per-wave
    __shared__ float klw[4];

    const int t = threadIdx.x;
    const int w = t >> 6, l = t & 63, g = l >> 4, li = l & 15;

    // ---- one-time staging ----
    if (t < 128) s_pgb[t] = make_float2(pre_g[t], pre_b[t]);
    for (int e = t; e < 2048; e += 256) {
        int nt = e >> 8, s = (e >> 6) & 3, ln = e & 63;
        const float* src = (nt < 4) ? W_mu : W_lv;
        int gg = ln >> 4, ll = ln & 15, c = ll + 16 * (nt & 3);
        unsigned int p[4];
#pragma unroll
        for (int jp = 0; jp < 4; ++jp) {
            int k = 32 * s + 8 * gg + 2 * jp;
            p[jp] = (unsigned)f2bf(src[k * 64 + c]) | ((unsigned)f2bf(src[(k + 1) * 64 + c]) << 16);
        }
        WmlB[e] = make_uint4(p[0], p[1], p[2], p[3]);
    }
    for (int e = t; e < 4096; e += 256) {
        int c = e >> 6, hp = e & 63;
        WvoP[e] = (unsigned)f2bf(wvo_ws[c * 128 + hp]) | ((unsigned)f2bf(wvo_ws[c * 128 + hp + 64]) << 16);
    }
    // lane-resident constants
    float bmu4[4], blv4[4], pg4[4], pb4[4];
#pragma unroll
    for (int nt = 0; nt < 4; ++nt) {
        int c = li + 16 * nt;
        bmu4[nt] = b_mu[c]; blv4[nt] = b_lv[c]; pg4[nt] = post_g[c]; pb4[nt] = post_b[c];
    }
    const float bo0 = bvo_ws[l], bo1 = bvo_ws[64 + l];
    __syncthreads();

    const f32x4 zero4 = {0.f, 0.f, 0.f, 0.f};
    const int stride = gridDim.x * 4;
    int bn = blockIdx.x * 4 + w;

    f32x4 nbr[2][4][2];      // rows li,16+li cols 32s+8g+4h..
    float epr[2][4][4];      // eps in MFMA-C layout: row=16mt+4g+r, col=li+16nt
    float qk4[4];            // qk[li+16nt]
    float trr;               // trust[l&31]

    {   // prologue prefetch
        const float* base = neighbor_feat + ((size_t)bn * NK + li) * NH + 8 * g;
#pragma unroll
        for (int t2 = 0; t2 < 2; ++t2)
#pragma unroll
            for (int s = 0; s < 4; ++s)
#pragma unroll
                for (int h = 0; h < 2; ++h)
                    nbr[t2][s][h] = *(const f32x4*)(base + (size_t)t2 * 16 * NH + 32 * s + 4 * h);
        const float* eb = eps_g + ((size_t)bn * NK + 4 * g) * NL + li;
#pragma unroll
        for (int mt = 0; mt < 2; ++mt)
#pragma unroll
            for (int nt = 0; nt < 4; ++nt)
#pragma unroll
                for (int r = 0; r < 4; ++r)
                    epr[mt][nt][r] = eb[(size_t)(16 * mt + r) * NL + 16 * nt];
#pragma unroll
        for (int nt = 0; nt < 4; ++nt) qk4[nt] = qk_ws[(size_t)bn * 64 + li + 16 * nt];
        trr = trust_mask[(size_t)bn * NK + (l & 31)];
    }

    float kl_acc = 0.f;

    for (; bn < NB; bn += stride) {
        const int nxt = (bn + stride < NB) ? bn + stride : bn;

        // ---- LN -> A-fragments in registers (reduce across g: xor16/32) ----
        float s0 = 0.f, s1 = 0.f;
#pragma unroll
        for (int s = 0; s < 4; ++s)
#pragma unroll
            for (int h = 0; h < 2; ++h) {
                f32x4 v0 = nbr[0][s][h], v1 = nbr[1][s][h];
                s0 += v0[0] + v0[1] + v0[2] + v0[3];
                s1 += v1[0] + v1[1] + v1[2] + v1[3];
            }
        s0 += __shfl_xor(s0, 16); s0 += __shfl_xor(s0, 32);
        s1 += __shfl_xor(s1, 16); s1 += __shfl_xor(s1, 32);
        float m0 = s0 * (1.f / 128.f), m1 = s1 * (1.f / 128.f);
        float v0s = 0.f, v1s = 0.f;
#pragma unroll
        for (int s = 0; s < 4; ++s)
#pragma unroll
            for (int h = 0; h < 2; ++h)
#pragma unroll
                for (int c = 0; c < 4; ++c) {
                    float d0 = nbr[0][s][h][c] - m0; v0s += d0 * d0;
                    float d1 = nbr[1][s][h][c] - m1; v1s += d1 * d1;
                }
        v0s += __shfl_xor(v0s, 16); v0s += __shfl_xor(v0s, 32);
        v1s += __shfl_xor(v1s, 16); v1s += __shfl_xor(v1s, 32);
        float inv0 = rsqrtf(v0s * (1.f / 128.f) + 1e-5f);
        float inv1 = rsqrtf(v1s * (1.f / 128.f) + 1e-5f);
        bf16x8 a0[4], a1[4];
#pragma unroll
        for (int s = 0; s < 4; ++s) {
            const float2* gbp = &s_pgb[32 * s + 8 * g];
#pragma unroll
            for (int h = 0; h < 2; ++h)
#pragma unroll
                for (int c = 0; c < 4; ++c) {
                    int j = 4 * h + c;
                    float2 gb = gbp[j];
                    a0[s][j] = (short)f2bf((nbr[0][s][h][c] - m0) * inv0 * gb.x + gb.y);
                    a1[s][j] = (short)f2bf((nbr[1][s][h][c] - m1) * inv1 * gb.x + gb.y);
                }
        }
        {   // reissue neighbor loads for next node
            const float* base = neighbor_feat + ((size_t)nxt * NK + li) * NH + 8 * g;
#pragma unroll
            for (int t2 = 0; t2 < 2; ++t2)
#pragma unroll
                for (int s = 0; s < 4; ++s)
#pragma unroll
                    for (int h = 0; h < 2; ++h)
                        nbr[t2][s][h] = *(const f32x4*)(base + (size_t)t2 * 16 * NH + 32 * s + 4 * h);
        }

        // ---- GEMM1: full 128 cols of [mu|lv] in this wave (B-frags from LDS blob) ----
        f32x4 acc1[2][8];
#pragma unroll
        for (int mt = 0; mt < 2; ++mt)
#pragma unroll
            for (int nt = 0; nt < 8; ++nt) acc1[mt][nt] = zero4;
#pragma unroll
        for (int s = 0; s < 4; ++s)
#pragma unroll
            for (int nt = 0; nt < 8; ++nt) {
                bf16x8 fb = *(const bf16x8*)&WmlB[(nt * 4 + s) * 64 + l];
                acc1[0][nt] = __builtin_amdgcn_mfma_f32_16x16x32_bf16(a0[s], fb, acc1[0][nt], 0, 0, 0);
                acc1[1][nt] = __builtin_amdgcn_mfma_f32_16x16x32_bf16(a1[s], fb, acc1[1][nt], 0, 0, 0);
            }

        // ---- reparam + KL (z replaces mu in acc1[..][nt<4]) ----
#pragma unroll
        for (int mt = 0; mt < 2; ++mt)
#pragma unroll
            for (int nt = 0; nt < 4; ++nt)
#pragma unroll
                for (int r = 0; r < 4; ++r) {
                    float mu = acc1[mt][nt][r] + bmu4[nt];
                    float lv = acc1[mt][nt + 4][r] + blv4[nt];
                    float eh = __expf(0.5f * lv);
                    kl_acc += 1.f + lv - mu * mu - eh * eh;
                    acc1[mt][nt][r] = mu + epr[mt][nt][r] * eh;
                }
        {   // reissue eps for next node
            const float* eb = eps_g + ((size_t)nxt * NK + 4 * g) * NL + li;
#pragma unroll
            for (int mt = 0; mt < 2; ++mt)
#pragma unroll
                for (int nt = 0; nt < 4; ++nt)
#pragma unroll
                    for (int r = 0; r < 4; ++r)
                        epr[mt][nt][r] = eb[(size_t)(16 * mt + r) * NL + 16 * nt];
        }

        // ---- post-LN per row (reduce across li: xor1..8), z stays in regs ----
#pragma unroll
        for (int mt = 0; mt < 2; ++mt)
#pragma unroll
            for (int r = 0; r < 4; ++r) {
                float s1r = acc1[mt][0][r] + acc1[mt][1][r] + acc1[mt][2][r] + acc1[mt][3][r];
                s1r += __shfl_xor(s1r, 1); s1r += __shfl_xor(s1r, 2);
                s1r += __shfl_xor(s1r, 4); s1r += __shfl_xor(s1r, 8);
                float mean = s1r * (1.f / 64.f);
                float s2r = 0.f;
#pragma unroll
                for (int nt = 0; nt < 4; ++nt) { float d = acc1[mt][nt][r] - mean; s2r += d * d; }
                s2r += __shfl_xor(s2r, 1); s2r += __shfl_xor(s2r, 2);
                s2r += __shfl_xor(s2r, 4); s2r += __shfl_xor(s2r, 8);
                float inv = rsqrtf(s2r * (1.f / 64.f) + 1e-5f);
#pragma unroll
                for (int nt = 0; nt < 4; ++nt)
                    acc1[mt][nt][r] = (acc1[mt][nt][r] - mean) * inv * pg4[nt] + pb4[nt];
            }

        // ---- logits: dot(z[row], qk) per row + trust ----
        float trlog = __logf(trr + 1e-6f);
        float att[2][4];
#pragma unroll
        for (int mt = 0; mt < 2; ++mt)
#pragma unroll
            for (int r = 0; r < 4; ++r) {
                float lg = acc1[mt][0][r] * qk4[0] + acc1[mt][1][r] * qk4[1]
                         + acc1[mt][2][r] * qk4[2] + acc1[mt][3][r] * qk4[3];
                lg += __shfl_xor(lg, 1); lg += __shfl_xor(lg, 2);
                lg += __shfl_xor(lg, 4); lg += __shfl_xor(lg, 8);
                att[mt][r] = lg * 0.125f + __shfl(trlog, 16 * mt + 4 * g + r);
            }
        {   // reissue qk + trust for next node
#pragma unroll
            for (int nt = 0; nt < 4; ++nt) qk4[nt] = qk_ws[(size_t)nxt * 64 + li + 16 * nt];
            trr = trust_mask[(size_t)nxt * NK + (l & 31)];
        }

        // ---- softmax across 32 rows (own-8 then xor16/32) ----
        float mx = att[0][0];
#pragma unroll
        for (int mt = 0; mt < 2; ++mt)
#pragma unroll
            for (int r = 0; r < 4; ++r) mx = fmaxf(mx, att[mt][r]);
        mx = fmaxf(mx, __shfl_xor(mx, 16)); mx = fmaxf(mx, __shfl_xor(mx, 32));
        float den = 0.f;
#pragma unroll
        for (int mt = 0; mt < 2; ++mt)
#pragma unroll
            for (int r = 0; r < 4; ++r) { att[mt][r] = __expf(att[mt][r] - mx); den += att[mt][r]; }
        den += __shfl_xor(den, 16); den += __shfl_xor(den, 32);
        float idn = 1.f / den;

        // ---- zbar[c] = sum_n att[n] z[n,c]  (own rows, then xor16/32) ----
#pragma unroll
        for (int nt = 0; nt < 4; ++nt) {
            float zb = 0.f;
#pragma unroll
            for (int mt = 0; mt < 2; ++mt)
#pragma unroll
                for (int r = 0; r < 4; ++r) zb += att[mt][r] * acc1[mt][nt][r];
            zb *= idn;
            zb += __shfl_xor(zb, 16); zb += __shfl_xor(zb, 32);
            if (g == 0) zbar_l[w][li + 16 * nt] = zb;
        }

        // ---- out = zbar @ Wvo + bvo  (same-wave LDS RAW; broadcast reads) ----
        float o0 = 0.f, o1 = 0.f;
#pragma unroll 8
        for (int c = 0; c < 64; ++c) {
            float zc = zbar_l[w][c];
            unsigned int W2 = WvoP[c * 64 + l];
            o0 += zc * bflo(W2);
            o1 += zc * bfhi(W2);
        }
        out[(size_t)bn * NH + l] = o0 + bo0;
        out[(size_t)bn * NH + 64 + l] = o1 + bo1;
    }

    // ---- KL reduction ----
#pragma unroll
    for (int msk = 1; msk < 64; msk <<= 1) kl_acc += __shfl_xor(kl_acc, msk);
    if (l == 0) klw[w] = kl_acc;
    __syncthreads();
    if (t == 0) {
        float tot = klw[0] + klw[1] + klw[2] + klw[3];
        atomicAdd(out + (size_t)NB * NH, tot * (-0.5f * 0.001f / ((float)NB * NK)));
    }
}

extern "C" void kernel_launch(void* const* d_in, const int* in_sizes, int n_in,
                              void* d_out, int out_size, void* d_ws, size_t ws_size,
                              hipStream_t stream) {
    const float* self_feat     = (const float*)d_in[0];
    const float* neighbor_feat = (const float*)d_in[1];
    const float* trust_mask    = (const float*)d_in[2];
    const float* eps           = (const float*)d_in[3];
    const float* pre_g  = (const float*)d_in[4];
    const float* pre_b  = (const float*)d_in[5];
    const float* W_mu   = (const float*)d_in[6];
    const float* b_mu   = (const float*)d_in[7];
    const float* W_lv   = (const float*)d_in[8];
    const float* b_lv   = (const float*)d_in[9];
    const float* post_g = (const float*)d_in[10];
    const float* post_b = (const float*)d_in[11];
    const float* W_q    = (const float*)d_in[12];
    const float* b_q    = (const float*)d_in[13];
    const float* W_k    = (const float*)d_in[14];
    const float* W_v    = (const float*)d_in[16];
    const float* b_v    = (const float*)d_in[17];
    const float* W_o    = (const float*)d_in[18];
    const float* b_o    = (const float*)d_in[19];
    float* out = (float*)d_out;

    // ws: qk f32 [NB,64] (12.8MB) | Wvo f32 [64,128] | bvo f32 [128]
    float* qk_ws  = (float*)d_ws;
    float* wvo_ws = qk_ws + (size_t)NB * 64;
    float* bvo_ws = wvo_ws + 64 * 128;

    hipLaunchKernelGGL(kl_zero_kernel, dim3(1), dim3(64), 0, stream, out);
    hipLaunchKernelGGL(wvo_kernel, dim3(1), dim3(256), 0, stream, W_v, W_o, b_v, b_o, wvo_ws, bvo_ws);
    hipLaunchKernelGGL(qk_kernel, dim3((NB + 31) / 32), dim3(256), 0, stream,
                       self_feat, W_q, b_q, W_k, qk_ws);
    hipLaunchKernelGGL(fzw_kernel, dim3(512), dim3(256), 0, stream,
                       neighbor_feat, trust_mask, eps, pre_g, pre_b,
                       W_mu, b_mu, W_lv, b_lv, post_g, post_b,
                       qk_ws, wvo_ws, bvo_ws, out);
}